// Round 1
// baseline (699.470 us; speedup 1.0000x reference)
//
#include <hip/hip_runtime.h>
#include <cstdint>
#include <cstddef>

#define FEAT 128
#define FOUT 40
constexpr float BN_EPS = 1e-5f;

// ---------------- CSR build ----------------

__global__ __launch_bounds__(256) void count_k(const int* __restrict__ dst, int* __restrict__ cnt, int E) {
    int e = blockIdx.x * 256 + threadIdx.x;
    if (e < E) atomicAdd(&cnt[dst[e]], 1);
}

__global__ __launch_bounds__(256) void scan1_k(const int* __restrict__ cnt, int* __restrict__ bsum, int n) {
    __shared__ int sh[256];
    int base = blockIdx.x * 1024, t = threadIdx.x;
    int s = 0;
#pragma unroll
    for (int j = 0; j < 4; ++j) {
        int idx = base + t * 4 + j;
        if (idx < n) s += cnt[idx];
    }
    sh[t] = s;
    __syncthreads();
    for (int o = 128; o > 0; o >>= 1) {
        if (t < o) sh[t] += sh[t + o];
        __syncthreads();
    }
    if (t == 0) bsum[blockIdx.x] = sh[0];
}

__global__ void scan2_k(const int* __restrict__ bsum, int* __restrict__ boff, int nb,
                        int* __restrict__ offs, int n, int E) {
    if (threadIdx.x == 0 && blockIdx.x == 0) {
        int run = 0;
        for (int i = 0; i < nb; ++i) { boff[i] = run; run += bsum[i]; }
        offs[n] = E;
    }
}

__global__ __launch_bounds__(256) void scan3_k(const int* __restrict__ cnt, const int* __restrict__ boff,
                                               int* __restrict__ offs, int n) {
    __shared__ int sh[256];
    int base = blockIdx.x * 1024, t = threadIdx.x;
    int c[4];
    int s = 0;
#pragma unroll
    for (int j = 0; j < 4; ++j) {
        int idx = base + t * 4 + j;
        c[j] = (idx < n) ? cnt[idx] : 0;
        s += c[j];
    }
    sh[t] = s;
    __syncthreads();
    for (int o = 1; o < 256; o <<= 1) {
        int v = (t >= o) ? sh[t - o] : 0;
        __syncthreads();
        sh[t] += v;
        __syncthreads();
    }
    int g = boff[blockIdx.x] + sh[t] - s;
#pragma unroll
    for (int j = 0; j < 4; ++j) {
        int idx = base + t * 4 + j;
        if (idx < n) offs[idx] = g;
        g += c[j];
    }
}

__global__ __launch_bounds__(256) void cursor_dinv_k(const int* __restrict__ offs, const int* __restrict__ cnt,
                                                     int* __restrict__ cursor, float* __restrict__ dinv, int n) {
    int i = blockIdx.x * 256 + threadIdx.x;
    if (i < n) {
        cursor[i] = offs[i];
        dinv[i] = rsqrtf((float)(cnt[i] + 1));   // deg includes self-loop; always >= 1
    }
}

__global__ __launch_bounds__(256) void fill_k(const int* __restrict__ src, const int* __restrict__ dst,
                                              int* __restrict__ cursor, int* __restrict__ csr, int E) {
    int e = blockIdx.x * 256 + threadIdx.x;
    if (e < E) {
        int d = dst[e];
        int p = atomicAdd(&cursor[d], 1);
        csr[p] = src[e];
    }
}

// ---------------- GEMM (fp32, LDS-staged), epilogue prescales by dinv[row] ----------------

__global__ __launch_bounds__(256) void gemm128_k(const float* __restrict__ X, const float* __restrict__ W,
                                                 const float* __restrict__ dinv, float* __restrict__ H, int n) {
    __shared__ float Ws[128 * 128];     // 64 KiB
    __shared__ float Xs[128][36];       // transposed X tile, padded (18 KiB)
    for (int i = threadIdx.x; i < 128 * 128 / 4; i += 256)
        ((float4*)Ws)[i] = ((const float4*)W)[i];

    const int ty = threadIdx.x >> 5;    // 0..7  -> rows ty*4..ty*4+3
    const int tx = threadIdx.x & 31;    // 0..31 -> cols tx*4..tx*4+3
    const int ntiles = n / 32;          // N=100000 -> 3125 exact
    for (int tile = blockIdx.x; tile < ntiles; tile += gridDim.x) {
        int row0 = tile * 32;
        __syncthreads();
        for (int i = threadIdx.x; i < 1024; i += 256) {   // 32 rows x 128 cols / 4
            int rr = i >> 5;
            int k4 = (i & 31) * 4;
            float4 v = ((const float4*)(X + (size_t)(row0 + rr) * FEAT))[i & 31];
            Xs[k4 + 0][rr] = v.x; Xs[k4 + 1][rr] = v.y; Xs[k4 + 2][rr] = v.z; Xs[k4 + 3][rr] = v.w;
        }
        __syncthreads();
        float acc[4][4] = {};
        for (int k = 0; k < 128; ++k) {
            float4 a = *(const float4*)&Xs[k][ty * 4];
            float4 b = *(const float4*)&Ws[k * 128 + tx * 4];
            acc[0][0] += a.x * b.x; acc[0][1] += a.x * b.y; acc[0][2] += a.x * b.z; acc[0][3] += a.x * b.w;
            acc[1][0] += a.y * b.x; acc[1][1] += a.y * b.y; acc[1][2] += a.y * b.z; acc[1][3] += a.y * b.w;
            acc[2][0] += a.z * b.x; acc[2][1] += a.z * b.y; acc[2][2] += a.z * b.z; acc[2][3] += a.z * b.w;
            acc[3][0] += a.w * b.x; acc[3][1] += a.w * b.y; acc[3][2] += a.w * b.z; acc[3][3] += a.w * b.w;
        }
#pragma unroll
        for (int i2 = 0; i2 < 4; ++i2) {
            int r = row0 + ty * 4 + i2;
            float dv = dinv[r];
            float4 o = make_float4(acc[i2][0] * dv, acc[i2][1] * dv, acc[i2][2] * dv, acc[i2][3] * dv);
            *(float4*)&H[(size_t)r * FEAT + tx * 4] = o;
        }
    }
}

__global__ __launch_bounds__(256) void gemm40_k(const float* __restrict__ X, const float* __restrict__ W,
                                                const float* __restrict__ dinv, float* __restrict__ H, int n) {
    __shared__ float Ws[128 * FOUT];    // 20 KiB
    __shared__ float Xs[128][36];       // 18 KiB
    for (int i = threadIdx.x; i < 128 * FOUT / 4; i += 256)
        ((float4*)Ws)[i] = ((const float4*)W)[i];

    const int r = threadIdx.x >> 3;     // 0..31
    const int cg = threadIdx.x & 7;     // 0..7 -> cols cg*5..cg*5+4
    const int ntiles = n / 32;
    for (int tile = blockIdx.x; tile < ntiles; tile += gridDim.x) {
        int row0 = tile * 32;
        __syncthreads();
        for (int i = threadIdx.x; i < 1024; i += 256) {
            int rr = i >> 5;
            int k4 = (i & 31) * 4;
            float4 v = ((const float4*)(X + (size_t)(row0 + rr) * FEAT))[i & 31];
            Xs[k4 + 0][rr] = v.x; Xs[k4 + 1][rr] = v.y; Xs[k4 + 2][rr] = v.z; Xs[k4 + 3][rr] = v.w;
        }
        __syncthreads();
        float acc[5] = {0.f, 0.f, 0.f, 0.f, 0.f};
        for (int k = 0; k < 128; ++k) {
            float a = Xs[k][r];
            const float* wrow = &Ws[k * FOUT + cg * 5];
#pragma unroll
            for (int j = 0; j < 5; ++j) acc[j] += a * wrow[j];
        }
        float dv = dinv[row0 + r];
#pragma unroll
        for (int j = 0; j < 5; ++j)
            H[(size_t)(row0 + r) * FOUT + cg * 5 + j] = acc[j] * dv;
    }
}

// ---------------- Aggregation: one 64-lane wave per destination node ----------------

__global__ __launch_bounds__(256) void agg128_k(const float* __restrict__ H, const int* __restrict__ offs,
                                                const int* __restrict__ csr, const float* __restrict__ dinv,
                                                const float* __restrict__ b, float* __restrict__ Z, int n) {
    int wid = (blockIdx.x * 256 + threadIdx.x) >> 6;
    int lane = threadIdx.x & 63;
    if (wid >= n) return;
    int beg = offs[wid], end = offs[wid + 1];
    const int f = lane * 2;
    float2 acc = *(const float2*)&H[(size_t)wid * FEAT + f];   // self-loop term (h' already * dinv)
    for (int e = beg; e < end; ++e) {
        int s = csr[e];
        float2 v = *(const float2*)&H[(size_t)s * FEAT + f];
        acc.x += v.x;
        acc.y += v.y;
    }
    float dv = dinv[wid];
    float2 o;
    o.x = acc.x * dv + b[f];
    o.y = acc.y * dv + b[f + 1];
    *(float2*)&Z[(size_t)wid * FEAT + f] = o;
}

__global__ __launch_bounds__(256) void agg40_softmax_k(const float* __restrict__ H, const int* __restrict__ offs,
                                                       const int* __restrict__ csr, const float* __restrict__ dinv,
                                                       const float* __restrict__ b, float* __restrict__ out, int n) {
    int wid = (blockIdx.x * 256 + threadIdx.x) >> 6;
    int lane = threadIdx.x & 63;
    if (wid >= n) return;
    int beg = offs[wid], end = offs[wid + 1];
    bool active = lane < FOUT;
    float acc = active ? H[(size_t)wid * FOUT + lane] : 0.f;
    for (int e = beg; e < end; ++e) {
        int s = csr[e];
        if (active) acc += H[(size_t)s * FOUT + lane];
    }
    float val = active ? (acc * dinv[wid] + b[lane]) : -INFINITY;
    float m = val;
#pragma unroll
    for (int o = 32; o > 0; o >>= 1) m = fmaxf(m, __shfl_xor(m, o));
    float ex = active ? expf(val - m) : 0.f;
    float ssum = ex;
#pragma unroll
    for (int o = 32; o > 0; o >>= 1) ssum += __shfl_xor(ssum, o);
    if (active) out[(size_t)wid * FOUT + lane] = val - m - logf(ssum);
}

// ---------------- BatchNorm ----------------

__global__ __launch_bounds__(256) void bnstats_k(const float* __restrict__ Z, float* __restrict__ sums, int n) {
    int c = threadIdx.x & 127;
    int r = blockIdx.x * 2 + (threadIdx.x >> 7);
    float s = 0.f, q = 0.f;
    for (; r < n; r += gridDim.x * 2) {
        float v = Z[(size_t)r * FEAT + c];
        s += v;
        q += v * v;
    }
    atomicAdd(&sums[c], s);
    atomicAdd(&sums[FEAT + c], q);
}

__global__ void bnfinal_k(const float* __restrict__ sums, const float* __restrict__ g,
                          const float* __restrict__ be, float* __restrict__ ss, int n) {
    int c = threadIdx.x;   // 128 threads
    float inv_n = 1.0f / (float)n;
    float mu = sums[c] * inv_n;
    float var = sums[FEAT + c] * inv_n - mu * mu;
    float rstd = rsqrtf(var + BN_EPS);
    float sc = g[c] * rstd;
    ss[c] = sc;
    ss[FEAT + c] = be[c] - mu * sc;
}

__global__ __launch_bounds__(256) void bnnorm_k(float* __restrict__ Z, const float* __restrict__ ss, int n) {
    int total = n * (FEAT / 4);
    for (int i = blockIdx.x * 256 + threadIdx.x; i < total; i += gridDim.x * 256) {
        int c4 = (i & 31) * 4;
        float4 v = ((float4*)Z)[i];
        float4 o;
        o.x = fmaxf(v.x * ss[c4 + 0] + ss[FEAT + c4 + 0], 0.f);
        o.y = fmaxf(v.y * ss[c4 + 1] + ss[FEAT + c4 + 1], 0.f);
        o.z = fmaxf(v.z * ss[c4 + 2] + ss[FEAT + c4 + 2], 0.f);
        o.w = fmaxf(v.w * ss[c4 + 3] + ss[FEAT + c4 + 3], 0.f);
        ((float4*)Z)[i] = o;
    }
}

// ---------------- launch ----------------

extern "C" void kernel_launch(void* const* d_in, const int* in_sizes, int n_in,
                              void* d_out, int out_size, void* d_ws, size_t ws_size,
                              hipStream_t stream) {
    const float* x   = (const float*)d_in[0];
    const int*   src = (const int*)d_in[1];
    const int*   dst = (const int*)d_in[2];
    const float* W1  = (const float*)d_in[3];
    const float* b1  = (const float*)d_in[4];
    const float* W2  = (const float*)d_in[5];
    const float* b2  = (const float*)d_in[6];
    const float* W3  = (const float*)d_in[7];
    const float* b3  = (const float*)d_in[8];
    const float* g1  = (const float*)d_in[9];
    const float* be1 = (const float*)d_in[10];
    const float* g2  = (const float*)d_in[11];
    const float* be2 = (const float*)d_in[12];

    const int N = in_sizes[0] / FEAT;
    const int E = in_sizes[1];
    float* out = (float*)d_out;

    char* p = (char*)d_ws;
    auto alloc = [&](size_t bytes) {
        char* r = p;
        p += (bytes + 255) & ~(size_t)255;
        return r;
    };
    float* dinv   = (float*)alloc((size_t)N * 4);
    int*   cnt    = (int*)alloc((size_t)N * 4);
    int*   offs   = (int*)alloc((size_t)(N + 1) * 4);
    int*   cursor = (int*)alloc((size_t)N * 4);
    int*   csr    = (int*)alloc((size_t)E * 4);
    int*   bsum   = (int*)alloc(1024);
    int*   boff   = (int*)alloc(1024);
    float* sums   = (float*)alloc(1024);
    float* ss     = (float*)alloc(1024);
    float* H      = (float*)alloc((size_t)N * FEAT * 4);
    float* Z      = (float*)alloc((size_t)N * FEAT * 4);

    const int nb = (N + 1023) / 1024;
    const int eb = (E + 255) / 256;
    const int wb = (N * 64 + 255) / 256;   // wave-per-node grids

    // CSR build + dinv
    hipMemsetAsync(cnt, 0, (size_t)N * 4, stream);
    count_k<<<eb, 256, 0, stream>>>(dst, cnt, E);
    scan1_k<<<nb, 256, 0, stream>>>(cnt, bsum, N);
    scan2_k<<<1, 64, 0, stream>>>(bsum, boff, nb, offs, N, E);
    scan3_k<<<nb, 256, 0, stream>>>(cnt, boff, offs, N);
    cursor_dinv_k<<<(N + 255) / 256, 256, 0, stream>>>(offs, cnt, cursor, dinv, N);
    fill_k<<<eb, 256, 0, stream>>>(src, dst, cursor, csr, E);

    // Layer 1
    gemm128_k<<<256, 256, 0, stream>>>(x, W1, dinv, H, N);
    agg128_k<<<wb, 256, 0, stream>>>(H, offs, csr, dinv, b1, Z, N);
    hipMemsetAsync(sums, 0, 1024, stream);
    bnstats_k<<<1024, 256, 0, stream>>>(Z, sums, N);
    bnfinal_k<<<1, 128, 0, stream>>>(sums, g1, be1, ss, N);
    bnnorm_k<<<2048, 256, 0, stream>>>(Z, ss, N);

    // Layer 2
    gemm128_k<<<256, 256, 0, stream>>>(Z, W2, dinv, H, N);
    agg128_k<<<wb, 256, 0, stream>>>(H, offs, csr, dinv, b2, Z, N);
    hipMemsetAsync(sums, 0, 1024, stream);
    bnstats_k<<<1024, 256, 0, stream>>>(Z, sums, N);
    bnfinal_k<<<1, 128, 0, stream>>>(sums, g2, be2, ss, N);
    bnnorm_k<<<2048, 256, 0, stream>>>(Z, ss, N);

    // Layer 3 + log_softmax
    gemm40_k<<<1024, 256, 0, stream>>>(Z, W3, dinv, H, N);
    agg40_softmax_k<<<wb, 256, 0, stream>>>(H, offs, csr, dinv, b3, out, N);
}

// Round 3
// 557.210 us; speedup vs baseline: 1.2553x; 1.2553x over previous
//
#include <hip/hip_runtime.h>
#include <cstdint>
#include <cstddef>

#define FEAT 128
#define FOUT 40
constexpr float BN_EPS = 1e-5f;

typedef __attribute__((ext_vector_type(8))) short bf16x8;
typedef __attribute__((ext_vector_type(4))) float f32x4;

__device__ __forceinline__ unsigned short f2bf(float f) {
    unsigned u = __float_as_uint(f);
    u += 0x7FFFu + ((u >> 16) & 1u);
    return (unsigned short)(u >> 16);
}
__device__ __forceinline__ float bflo(unsigned u) { return __uint_as_float(u << 16); }
__device__ __forceinline__ float bfhi(unsigned u) { return __uint_as_float(u & 0xFFFF0000u); }
__device__ __forceinline__ unsigned packbf2(float a, float b) {
    return (unsigned)f2bf(a) | ((unsigned)f2bf(b) << 16);
}

// ---------------- CSR build ----------------

__global__ __launch_bounds__(256) void count_k(const int* __restrict__ dst, int* __restrict__ cnt, int E) {
    int e = blockIdx.x * 256 + threadIdx.x;
    if (e < E) atomicAdd(&cnt[dst[e]], 1);
}

__global__ __launch_bounds__(256) void scan1_k(const int* __restrict__ cnt, int* __restrict__ bsum, int n) {
    __shared__ int sh[256];
    int base = blockIdx.x * 1024, t = threadIdx.x;
    int s = 0;
#pragma unroll
    for (int j = 0; j < 4; ++j) {
        int idx = base + t * 4 + j;
        if (idx < n) s += cnt[idx];
    }
    sh[t] = s;
    __syncthreads();
    for (int o = 128; o > 0; o >>= 1) {
        if (t < o) sh[t] += sh[t + o];
        __syncthreads();
    }
    if (t == 0) bsum[blockIdx.x] = sh[0];
}

__global__ void scan2_k(const int* __restrict__ bsum, int* __restrict__ boff, int nb,
                        int* __restrict__ offs, int n, int E) {
    if (threadIdx.x == 0 && blockIdx.x == 0) {
        int run = 0;
        for (int i = 0; i < nb; ++i) { boff[i] = run; run += bsum[i]; }
        offs[n] = E;
    }
}

__global__ __launch_bounds__(256) void scan3_k(const int* __restrict__ cnt, const int* __restrict__ boff,
                                               int* __restrict__ offs, int n) {
    __shared__ int sh[256];
    int base = blockIdx.x * 1024, t = threadIdx.x;
    int c[4];
    int s = 0;
#pragma unroll
    for (int j = 0; j < 4; ++j) {
        int idx = base + t * 4 + j;
        c[j] = (idx < n) ? cnt[idx] : 0;
        s += c[j];
    }
    sh[t] = s;
    __syncthreads();
    for (int o = 1; o < 256; o <<= 1) {
        int v = (t >= o) ? sh[t - o] : 0;
        __syncthreads();
        sh[t] += v;
        __syncthreads();
    }
    int g = boff[blockIdx.x] + sh[t] - s;
#pragma unroll
    for (int j = 0; j < 4; ++j) {
        int idx = base + t * 4 + j;
        if (idx < n) offs[idx] = g;
        g += c[j];
    }
}

__global__ __launch_bounds__(256) void cursor_dinv_k(const int* __restrict__ offs, const int* __restrict__ cnt,
                                                     int* __restrict__ cursor, float* __restrict__ dinv, int n) {
    int i = blockIdx.x * 256 + threadIdx.x;
    if (i < n) {
        cursor[i] = offs[i];
        dinv[i] = rsqrtf((float)(cnt[i] + 1));
    }
}

__global__ __launch_bounds__(256) void fill_k(const int* __restrict__ src, const int* __restrict__ dst,
                                              int* __restrict__ cursor, int* __restrict__ csr, int E) {
    int e = blockIdx.x * 256 + threadIdx.x;
    if (e < E) {
        int d = dst[e];
        int p = atomicAdd(&cursor[d], 1);
        csr[p] = src[e];
    }
}

// ---------------- weight pack to bf16 MFMA B-fragment order ----------------
// Wt layout: [kt 0..3][q 0..3][col][j 0..7], element = W[kt*32+q*8+j][col]

__global__ __launch_bounds__(256) void castW_k(const float* __restrict__ W1, const float* __restrict__ W2,
                                               const float* __restrict__ W3,
                                               unsigned short* __restrict__ Wt1, unsigned short* __restrict__ Wt2,
                                               unsigned short* __restrict__ Wt3) {
    int tid = blockIdx.x * 256 + threadIdx.x;
    int stride = gridDim.x * 256;
    for (int i = tid; i < 4 * 4 * 128 * 8; i += stride) {
        int j = i & 7, c = (i >> 3) & 127, q = (i >> 10) & 3, kt = i >> 12;
        int k = kt * 32 + q * 8 + j;
        Wt1[i] = f2bf(W1[k * 128 + c]);
        Wt2[i] = f2bf(W2[k * 128 + c]);
    }
    for (int i = tid; i < 4 * 4 * 48 * 8; i += stride) {
        int j = i & 7, rest = i >> 3;
        int c = rest % 48, kq = rest / 48;
        int q = kq & 3, kt = kq >> 2;
        int k = kt * 32 + q * 8 + j;
        Wt3[i] = (c < FOUT) ? f2bf(W3[k * FOUT + c]) : (unsigned short)0;
    }
}

// ---------------- MFMA GEMM 128x128, epilogue * dinv, bf16 out ----------------
// SRC 0: read fp32 (layer 1).  SRC 1: read bf16 + fused BN(scale/shift)+ReLU.

template <int SRC>
__global__ __launch_bounds__(256, 3) void gemm128_k(const void* __restrict__ srcp,
                                                    const unsigned short* __restrict__ Wt,
                                                    const float* __restrict__ ss,
                                                    const float* __restrict__ dinv,
                                                    unsigned short* __restrict__ Hb,
                                                    int ntiles, int nreal) {
    __shared__ uint4 XsU[64 * 16];              // 16 KiB, chunk-swizzled
    unsigned short* Xs = (unsigned short*)XsU;

    const int t = threadIdx.x;
    const int tc = t & 15;                      // chunk (8 cols) this thread stages
    const int l = t & 63, w = t >> 6;
    const int wm = w >> 1, wn = w & 1;
    const int lr = l & 15, q = l >> 4;

    float sc[8], sh[8];
    if (SRC == 1) {
#pragma unroll
        for (int j = 0; j < 8; ++j) { sc[j] = ss[tc * 8 + j]; sh[j] = ss[128 + tc * 8 + j]; }
    }

    // B fragments held in registers for the whole kernel (W is tile-invariant)
    bf16x8 Bf[4][4];
#pragma unroll
    for (int kt = 0; kt < 4; ++kt)
#pragma unroll
        for (int n = 0; n < 4; ++n) {
            int col = wn * 64 + n * 16 + lr;
            Bf[kt][n] = *(const bf16x8*)&((const uint4*)Wt)[(kt * 4 + q) * 128 + col];
        }

    for (int tile = blockIdx.x; tile < ntiles; tile += gridDim.x) {
        const int row0 = tile * 64;
        __syncthreads();
        // ---- stage 64x128 X tile (reg -> LDS, swizzled), fusing cast / BN+ReLU ----
#pragma unroll
        for (int k2 = 0; k2 < 4; ++k2) {
            int row = (t >> 4) + k2 * 16;
            int grow = row0 + row;
            uint4 o;
            if (SRC == 0) {
                if (grow < nreal) {
                    const float4* xp = (const float4*)((const float*)srcp + (size_t)grow * FEAT + tc * 8);
                    float4 f0 = xp[0], f1 = xp[1];
                    o.x = packbf2(f0.x, f0.y); o.y = packbf2(f0.z, f0.w);
                    o.z = packbf2(f1.x, f1.y); o.w = packbf2(f1.z, f1.w);
                } else {
                    o.x = 0u; o.y = 0u; o.z = 0u; o.w = 0u;
                }
            } else {
                uint4 u = ((const uint4*)((const unsigned short*)srcp + (size_t)grow * FEAT))[tc];
                float v0 = fmaxf(fmaf(bflo(u.x), sc[0], sh[0]), 0.f);
                float v1 = fmaxf(fmaf(bfhi(u.x), sc[1], sh[1]), 0.f);
                float v2 = fmaxf(fmaf(bflo(u.y), sc[2], sh[2]), 0.f);
                float v3 = fmaxf(fmaf(bfhi(u.y), sc[3], sh[3]), 0.f);
                float v4 = fmaxf(fmaf(bflo(u.z), sc[4], sh[4]), 0.f);
                float v5 = fmaxf(fmaf(bfhi(u.z), sc[5], sh[5]), 0.f);
                float v6 = fmaxf(fmaf(bflo(u.w), sc[6], sh[6]), 0.f);
                float v7 = fmaxf(fmaf(bfhi(u.w), sc[7], sh[7]), 0.f);
                o.x = packbf2(v0, v1); o.y = packbf2(v2, v3);
                o.z = packbf2(v4, v5); o.w = packbf2(v6, v7);
            }
            XsU[row * 16 + (tc ^ (row & 7))] = o;
        }
        __syncthreads();

        // ---- MFMA: wave computes 32 rows x 64 cols ----
        f32x4 acc[2][4];
#pragma unroll
        for (int m = 0; m < 2; ++m)
#pragma unroll
            for (int n = 0; n < 4; ++n)
#pragma unroll
                for (int r2 = 0; r2 < 4; ++r2) acc[m][n][r2] = 0.f;

#pragma unroll
        for (int kt = 0; kt < 4; ++kt) {
            int rowA = wm * 32 + lr;
            bf16x8 A0 = *(const bf16x8*)&XsU[rowA * 16 + ((kt * 4 + q) ^ (rowA & 7))];
            int rowB = rowA + 16;
            bf16x8 A1 = *(const bf16x8*)&XsU[rowB * 16 + ((kt * 4 + q) ^ (rowB & 7))];
#pragma unroll
            for (int n = 0; n < 4; ++n) {
                acc[0][n] = __builtin_amdgcn_mfma_f32_16x16x32_bf16(A0, Bf[kt][n], acc[0][n], 0, 0, 0);
                acc[1][n] = __builtin_amdgcn_mfma_f32_16x16x32_bf16(A1, Bf[kt][n], acc[1][n], 0, 0, 0);
            }
        }
        __syncthreads();

        // ---- epilogue: *dinv, bf16, transpose via LDS, vector store ----
#pragma unroll
        for (int m = 0; m < 2; ++m) {
            float dv[4];
#pragma unroll
            for (int r = 0; r < 4; ++r) dv[r] = dinv[row0 + wm * 32 + m * 16 + q * 4 + r];
#pragma unroll
            for (int n = 0; n < 4; ++n) {
                int col = wn * 64 + n * 16 + lr;
#pragma unroll
                for (int r = 0; r < 4; ++r) {
                    int row = wm * 32 + m * 16 + q * 4 + r;
                    Xs[row * 128 + (((col >> 3) ^ (row & 7)) << 3) + (col & 7)] = f2bf(acc[m][n][r] * dv[r]);
                }
            }
        }
        __syncthreads();
#pragma unroll
        for (int k2 = 0; k2 < 4; ++k2) {
            int row = (t >> 4) + k2 * 16;
            ((uint4*)&Hb[(size_t)(row0 + row) * FEAT])[tc] = XsU[row * 16 + (tc ^ (row & 7))];
        }
    }
}

// ---------------- MFMA GEMM 128x40 (padded to 48), fused BN+ReLU on load ----------------

__global__ __launch_bounds__(256, 4) void gemm40_k(const unsigned short* __restrict__ srcp,
                                                   const unsigned short* __restrict__ Wt,
                                                   const float* __restrict__ ss,
                                                   const float* __restrict__ dinv,
                                                   unsigned short* __restrict__ H3,
                                                   int ntiles) {
    __shared__ uint4 XsU[64 * 16];
    unsigned short* Xs = (unsigned short*)XsU;
    const int t = threadIdx.x, tc = t & 15;
    const int l = t & 63, w = t >> 6, lr = l & 15, q = l >> 4;

    float sc[8], sh[8];
#pragma unroll
    for (int j = 0; j < 8; ++j) { sc[j] = ss[tc * 8 + j]; sh[j] = ss[128 + tc * 8 + j]; }

    bf16x8 Bf[4][3];
#pragma unroll
    for (int kt = 0; kt < 4; ++kt)
#pragma unroll
        for (int n = 0; n < 3; ++n)
            Bf[kt][n] = *(const bf16x8*)&((const uint4*)Wt)[(kt * 4 + q) * 48 + n * 16 + lr];

    for (int tile = blockIdx.x; tile < ntiles; tile += gridDim.x) {
        const int row0 = tile * 64;
        __syncthreads();
#pragma unroll
        for (int k2 = 0; k2 < 4; ++k2) {
            int row = (t >> 4) + k2 * 16;
            int grow = row0 + row;
            uint4 u = ((const uint4*)(srcp + (size_t)grow * FEAT))[tc];
            float v0 = fmaxf(fmaf(bflo(u.x), sc[0], sh[0]), 0.f);
            float v1 = fmaxf(fmaf(bfhi(u.x), sc[1], sh[1]), 0.f);
            float v2 = fmaxf(fmaf(bflo(u.y), sc[2], sh[2]), 0.f);
            float v3 = fmaxf(fmaf(bfhi(u.y), sc[3], sh[3]), 0.f);
            float v4 = fmaxf(fmaf(bflo(u.z), sc[4], sh[4]), 0.f);
            float v5 = fmaxf(fmaf(bfhi(u.z), sc[5], sh[5]), 0.f);
            float v6 = fmaxf(fmaf(bflo(u.w), sc[6], sh[6]), 0.f);
            float v7 = fmaxf(fmaf(bfhi(u.w), sc[7], sh[7]), 0.f);
            uint4 o;
            o.x = packbf2(v0, v1); o.y = packbf2(v2, v3);
            o.z = packbf2(v4, v5); o.w = packbf2(v6, v7);
            XsU[row * 16 + (tc ^ (row & 7))] = o;
        }
        __syncthreads();

        f32x4 acc[3];
#pragma unroll
        for (int n = 0; n < 3; ++n)
#pragma unroll
            for (int r2 = 0; r2 < 4; ++r2) acc[n][r2] = 0.f;

#pragma unroll
        for (int kt = 0; kt < 4; ++kt) {
            int row = w * 16 + lr;
            bf16x8 A = *(const bf16x8*)&XsU[row * 16 + ((kt * 4 + q) ^ (row & 7))];
#pragma unroll
            for (int n = 0; n < 3; ++n)
                acc[n] = __builtin_amdgcn_mfma_f32_16x16x32_bf16(A, Bf[kt][n], acc[n], 0, 0, 0);
        }
        __syncthreads();

        float dv[4];
#pragma unroll
        for (int r = 0; r < 4; ++r) dv[r] = dinv[row0 + w * 16 + q * 4 + r];
#pragma unroll
        for (int n = 0; n < 3; ++n) {
            int col = n * 16 + lr;
#pragma unroll
            for (int r = 0; r < 4; ++r) {
                int row = w * 16 + q * 4 + r;
                Xs[row * 128 + (((col >> 3) ^ (row & 7)) << 3) + (col & 7)] = f2bf(acc[n][r] * dv[r]);
            }
        }
        __syncthreads();
        // store 6 chunks/row = 48 cols (FIX: was 3 chunks = 24 cols, dropping feats 24..39)
        for (int i = t; i < 384; i += 256) {
            int row = i / 6, cc = i - row * 6;
            ((uint4*)&H3[(size_t)(row0 + row) * 64])[cc] = XsU[row * 16 + (cc ^ (row & 7))];
        }
    }
}

// ---------------- aggregation (wave per node) + fused BN statistics ----------------

__global__ __launch_bounds__(256) void agg128_k(const unsigned* __restrict__ Hb, const int* __restrict__ offs,
                                                const int* __restrict__ csr, const float* __restrict__ dinv,
                                                const float* __restrict__ bias, unsigned* __restrict__ Zb,
                                                float* __restrict__ sums, int n) {
    const int l = threadIdx.x & 63, w = threadIdx.x >> 6;
    float bx = bias[2 * l], by = bias[2 * l + 1];
    float sx = 0.f, sy = 0.f, qx = 0.f, qy = 0.f;
    for (int node = blockIdx.x * 4 + w; node < n; node += gridDim.x * 4) {
        int beg = offs[node], end = offs[node + 1];
        unsigned u = Hb[(size_t)node * 64 + l];
        float ax = bflo(u), ay = bfhi(u);
        for (int e = beg; e < end; ++e) {
            int s = csr[e];
            unsigned v = Hb[(size_t)s * 64 + l];
            ax += bflo(v);
            ay += bfhi(v);
        }
        float dv = dinv[node];
        float zx = fmaf(ax, dv, bx), zy = fmaf(ay, dv, by);
        sx += zx; sy += zy; qx += zx * zx; qy += zy * zy;
        Zb[(size_t)node * 64 + l] = packbf2(zx, zy);
    }
    __shared__ float red[4][64][4];
    red[w][l][0] = sx; red[w][l][1] = sy; red[w][l][2] = qx; red[w][l][3] = qy;
    __syncthreads();
    if (threadIdx.x < 64) {
        int tt = threadIdx.x;
        float SX = 0.f, SY = 0.f, QX = 0.f, QY = 0.f;
#pragma unroll
        for (int ww = 0; ww < 4; ++ww) {
            SX += red[ww][tt][0]; SY += red[ww][tt][1];
            QX += red[ww][tt][2]; QY += red[ww][tt][3];
        }
        atomicAdd(&sums[2 * tt], SX);
        atomicAdd(&sums[2 * tt + 1], SY);
        atomicAdd(&sums[128 + 2 * tt], QX);
        atomicAdd(&sums[128 + 2 * tt + 1], QY);
    }
}

__global__ void bnfinal_k(const float* __restrict__ sums, const float* __restrict__ g,
                          const float* __restrict__ be, float* __restrict__ ss, int n) {
    int c = threadIdx.x;   // 128 threads
    float inv_n = 1.0f / (float)n;
    float mu = sums[c] * inv_n;
    float var = sums[128 + c] * inv_n - mu * mu;
    float rstd = rsqrtf(var + BN_EPS);
    float scv = g[c] * rstd;
    ss[c] = scv;
    ss[128 + c] = be[c] - mu * scv;
}

__global__ __launch_bounds__(256) void agg40_k(const unsigned short* __restrict__ H3, const int* __restrict__ offs,
                                               const int* __restrict__ csr, const float* __restrict__ dinv,
                                               const float* __restrict__ bias, float* __restrict__ out, int n) {
    const int l = threadIdx.x & 63, w = threadIdx.x >> 6;
    const bool act = l < FOUT;
    float bl = act ? bias[l] : 0.f;
    for (int node = blockIdx.x * 4 + w; node < n; node += gridDim.x * 4) {
        int beg = offs[node], end = offs[node + 1];
        float acc = act ? bflo((unsigned)H3[(size_t)node * 64 + l]) : 0.f;
        for (int e = beg; e < end; ++e) {
            int s = csr[e];
            if (act) acc += bflo((unsigned)H3[(size_t)s * 64 + l]);
        }
        float val = act ? fmaf(acc, dinv[node], bl) : -INFINITY;
        float m = val;
#pragma unroll
        for (int o = 32; o > 0; o >>= 1) m = fmaxf(m, __shfl_xor(m, o));
        float ex = act ? expf(val - m) : 0.f;
        float ssum = ex;
#pragma unroll
        for (int o = 32; o > 0; o >>= 1) ssum += __shfl_xor(ssum, o);
        if (act) out[(size_t)node * FOUT + l] = val - m - logf(ssum);
    }
}

// ---------------- launch ----------------

extern "C" void kernel_launch(void* const* d_in, const int* in_sizes, int n_in,
                              void* d_out, int out_size, void* d_ws, size_t ws_size,
                              hipStream_t stream) {
    const float* x   = (const float*)d_in[0];
    const int*   src = (const int*)d_in[1];
    const int*   dst = (const int*)d_in[2];
    const float* W1  = (const float*)d_in[3];
    const float* b1  = (const float*)d_in[4];
    const float* W2  = (const float*)d_in[5];
    const float* b2  = (const float*)d_in[6];
    const float* W3  = (const float*)d_in[7];
    const float* b3  = (const float*)d_in[8];
    const float* g1  = (const float*)d_in[9];
    const float* be1 = (const float*)d_in[10];
    const float* g2  = (const float*)d_in[11];
    const float* be2 = (const float*)d_in[12];

    const int N = in_sizes[0] / FEAT;
    const int E = in_sizes[1];
    const int Np = (N + 63) & ~63;
    const int ntiles = Np / 64;
    float* out = (float*)d_out;

    char* p = (char*)d_ws;
    auto alloc = [&](size_t bytes) {
        char* r = p;
        p += (bytes + 255) & ~(size_t)255;
        return r;
    };
    float* dinv   = (float*)alloc((size_t)Np * 4);
    int*   cnt    = (int*)alloc((size_t)N * 4);
    int*   offs   = (int*)alloc((size_t)(N + 1) * 4);
    int*   cursor = (int*)alloc((size_t)N * 4);
    int*   csr    = (int*)alloc((size_t)E * 4);
    int*   bsum   = (int*)alloc(1024);
    int*   boff   = (int*)alloc(1024);
    float* sums   = (float*)alloc(1024);
    float* ss     = (float*)alloc(1024);
    unsigned short* Wt1 = (unsigned short*)alloc(4 * 4 * 128 * 8 * 2);
    unsigned short* Wt2 = (unsigned short*)alloc(4 * 4 * 128 * 8 * 2);
    unsigned short* Wt3 = (unsigned short*)alloc(4 * 4 * 48 * 8 * 2);
    unsigned short* Hb  = (unsigned short*)alloc((size_t)Np * FEAT * 2);
    unsigned short* Zb  = (unsigned short*)alloc((size_t)Np * FEAT * 2);
    unsigned short* H3  = (unsigned short*)alloc((size_t)Np * 64 * 2);

    const int nb = (N + 1023) / 1024;
    const int eb = (E + 255) / 256;

    // CSR build + dinv
    hipMemsetAsync(cnt, 0, (size_t)N * 4, stream);
    count_k<<<eb, 256, 0, stream>>>(dst, cnt, E);
    scan1_k<<<nb, 256, 0, stream>>>(cnt, bsum, N);
    scan2_k<<<1, 64, 0, stream>>>(bsum, boff, nb, offs, N, E);
    scan3_k<<<nb, 256, 0, stream>>>(cnt, boff, offs, N);
    cursor_dinv_k<<<(N + 255) / 256, 256, 0, stream>>>(offs, cnt, cursor, dinv, N);
    fill_k<<<eb, 256, 0, stream>>>(src, dst, cursor, csr, E);
    castW_k<<<48, 256, 0, stream>>>(W1, W2, W3, Wt1, Wt2, Wt3);

    // Layer 1
    gemm128_k<0><<<768, 256, 0, stream>>>(x, Wt1, nullptr, dinv, Hb, ntiles, N);
    hipMemsetAsync(sums, 0, 1024, stream);
    agg128_k<<<1024, 256, 0, stream>>>((const unsigned*)Hb, offs, csr, dinv, b1, (unsigned*)Zb, sums, N);
    bnfinal_k<<<1, 128, 0, stream>>>(sums, g1, be1, ss, N);

    // Layer 2 (BN1+ReLU fused into staging)
    gemm128_k<1><<<768, 256, 0, stream>>>(Zb, Wt2, ss, dinv, Hb, ntiles, N);
    hipMemsetAsync(sums, 0, 1024, stream);
    agg128_k<<<1024, 256, 0, stream>>>((const unsigned*)Hb, offs, csr, dinv, b2, (unsigned*)Zb, sums, N);
    bnfinal_k<<<1, 128, 0, stream>>>(sums, g2, be2, ss, N);

    // Layer 3 (BN2+ReLU fused into staging) + log_softmax
    gemm40_k<<<1024, 256, 0, stream>>>(Zb, Wt3, ss, dinv, H3, ntiles);
    agg40_k<<<1024, 256, 0, stream>>>(H3, offs, csr, dinv, b3, out, N);
}

// Round 4
// 431.075 us; speedup vs baseline: 1.6226x; 1.2926x over previous
//
#include <hip/hip_runtime.h>
#include <cstdint>
#include <cstddef>

#define FEAT 128
#define FOUT 40
constexpr float BN_EPS = 1e-5f;

typedef __attribute__((ext_vector_type(8))) short bf16x8;
typedef __attribute__((ext_vector_type(4))) float f32x4;

__device__ __forceinline__ unsigned short f2bf(float f) {
    unsigned u = __float_as_uint(f);
    u += 0x7FFFu + ((u >> 16) & 1u);
    return (unsigned short)(u >> 16);
}
__device__ __forceinline__ float bflo(unsigned u) { return __uint_as_float(u << 16); }
__device__ __forceinline__ float bfhi(unsigned u) { return __uint_as_float(u & 0xFFFF0000u); }
__device__ __forceinline__ unsigned packbf2(float a, float b) {
    return (unsigned)f2bf(a) | ((unsigned)f2bf(b) << 16);
}

// ---------------- CSR build ----------------

__global__ __launch_bounds__(256) void count_k(const int* __restrict__ dst, int* __restrict__ cnt, int E) {
    int e = blockIdx.x * 256 + threadIdx.x;
    if (e < E) atomicAdd(&cnt[dst[e]], 1);
}

__global__ __launch_bounds__(256) void scan1_k(const int* __restrict__ cnt, int* __restrict__ bsum, int n) {
    __shared__ int sh[256];
    int base = blockIdx.x * 1024, t = threadIdx.x;
    int s = 0;
#pragma unroll
    for (int j = 0; j < 4; ++j) {
        int idx = base + t * 4 + j;
        if (idx < n) s += cnt[idx];
    }
    sh[t] = s;
    __syncthreads();
    for (int o = 128; o > 0; o >>= 1) {
        if (t < o) sh[t] += sh[t + o];
        __syncthreads();
    }
    if (t == 0) bsum[blockIdx.x] = sh[0];
}

// parallel block-sum scan (nb <= 256 for N <= 262144; serial fallback otherwise)
__global__ void scan2_k(const int* __restrict__ bsum, int* __restrict__ boff, int nb,
                        int* __restrict__ offs, int n, int E) {
    __shared__ int sh[256];
    int t = threadIdx.x;
    if (nb <= 256) {
        int v = (t < nb) ? bsum[t] : 0;
        sh[t] = v;
        __syncthreads();
        for (int o = 1; o < 256; o <<= 1) {
            int x = (t >= o) ? sh[t - o] : 0;
            __syncthreads();
            sh[t] += x;
            __syncthreads();
        }
        if (t < nb) boff[t] = sh[t] - v;
        if (t == 0) offs[n] = E;
    } else if (t == 0) {
        int run = 0;
        for (int i = 0; i < nb; ++i) { boff[i] = run; run += bsum[i]; }
        offs[n] = E;
    }
}

__global__ __launch_bounds__(256) void scan3_k(const int* __restrict__ cnt, const int* __restrict__ boff,
                                               int* __restrict__ offs, int n) {
    __shared__ int sh[256];
    int base = blockIdx.x * 1024, t = threadIdx.x;
    int c[4];
    int s = 0;
#pragma unroll
    for (int j = 0; j < 4; ++j) {
        int idx = base + t * 4 + j;
        c[j] = (idx < n) ? cnt[idx] : 0;
        s += c[j];
    }
    sh[t] = s;
    __syncthreads();
    for (int o = 1; o < 256; o <<= 1) {
        int v = (t >= o) ? sh[t - o] : 0;
        __syncthreads();
        sh[t] += v;
        __syncthreads();
    }
    int g = boff[blockIdx.x] + sh[t] - s;
#pragma unroll
    for (int j = 0; j < 4; ++j) {
        int idx = base + t * 4 + j;
        if (idx < n) offs[idx] = g;
        g += c[j];
    }
}

__global__ __launch_bounds__(256) void cursor_dinv_k(const int* __restrict__ offs, const int* __restrict__ cnt,
                                                     int* __restrict__ cursor, float* __restrict__ dinv, int n) {
    int i = blockIdx.x * 256 + threadIdx.x;
    if (i < n) {
        cursor[i] = offs[i];
        dinv[i] = rsqrtf((float)(cnt[i] + 1));
    }
}

__global__ __launch_bounds__(256) void fill_k(const int* __restrict__ src, const int* __restrict__ dst,
                                              int* __restrict__ cursor, int* __restrict__ csr, int E) {
    int e = blockIdx.x * 256 + threadIdx.x;
    if (e < E) {
        int d = dst[e];
        int p = atomicAdd(&cursor[d], 1);
        csr[p] = src[e];
    }
}

// ---------------- weight pack to bf16 MFMA B-fragment order ----------------
// Wt layout: [kt 0..3][q 0..3][col][j 0..7], element = W[kt*32+q*8+j][col]

__global__ __launch_bounds__(256) void castW_k(const float* __restrict__ W1, const float* __restrict__ W2,
                                               const float* __restrict__ W3,
                                               unsigned short* __restrict__ Wt1, unsigned short* __restrict__ Wt2,
                                               unsigned short* __restrict__ Wt3) {
    int tid = blockIdx.x * 256 + threadIdx.x;
    int stride = gridDim.x * 256;
    for (int i = tid; i < 4 * 4 * 128 * 8; i += stride) {
        int j = i & 7, c = (i >> 3) & 127, q = (i >> 10) & 3, kt = i >> 12;
        int k = kt * 32 + q * 8 + j;
        Wt1[i] = f2bf(W1[k * 128 + c]);
        Wt2[i] = f2bf(W2[k * 128 + c]);
    }
    for (int i = tid; i < 4 * 4 * 48 * 8; i += stride) {
        int j = i & 7, rest = i >> 3;
        int c = rest % 48, kq = rest / 48;
        int q = kq & 3, kt = kq >> 2;
        int k = kt * 32 + q * 8 + j;
        Wt3[i] = (c < FOUT) ? f2bf(W3[k * FOUT + c]) : (unsigned short)0;
    }
}

// ---------------- MFMA GEMM 128x128, epilogue * dinv, bf16 out ----------------
// SRC 0: read fp32 (layer 1).  SRC 1: read bf16 + fused BN(scale/shift)+ReLU.

template <int SRC>
__global__ __launch_bounds__(256, 3) void gemm128_k(const void* __restrict__ srcp,
                                                    const unsigned short* __restrict__ Wt,
                                                    const float* __restrict__ ss,
                                                    const float* __restrict__ dinv,
                                                    unsigned short* __restrict__ Hb,
                                                    int ntiles, int nreal) {
    __shared__ uint4 XsU[64 * 16];              // 16 KiB, chunk-swizzled
    unsigned short* Xs = (unsigned short*)XsU;

    const int t = threadIdx.x;
    const int tc = t & 15;                      // chunk (8 cols) this thread stages
    const int l = t & 63, w = t >> 6;
    const int wm = w >> 1, wn = w & 1;
    const int lr = l & 15, q = l >> 4;

    float sc[8], sh[8];
    if (SRC == 1) {
#pragma unroll
        for (int j = 0; j < 8; ++j) { sc[j] = ss[tc * 8 + j]; sh[j] = ss[128 + tc * 8 + j]; }
    }

    // B fragments held in registers for the whole kernel (W is tile-invariant)
    bf16x8 Bf[4][4];
#pragma unroll
    for (int kt = 0; kt < 4; ++kt)
#pragma unroll
        for (int n = 0; n < 4; ++n) {
            int col = wn * 64 + n * 16 + lr;
            Bf[kt][n] = *(const bf16x8*)&((const uint4*)Wt)[(kt * 4 + q) * 128 + col];
        }

    for (int tile = blockIdx.x; tile < ntiles; tile += gridDim.x) {
        const int row0 = tile * 64;
        __syncthreads();
        // ---- stage 64x128 X tile (reg -> LDS, swizzled), fusing cast / BN+ReLU ----
#pragma unroll
        for (int k2 = 0; k2 < 4; ++k2) {
            int row = (t >> 4) + k2 * 16;
            int grow = row0 + row;
            uint4 o;
            if (SRC == 0) {
                if (grow < nreal) {
                    const float4* xp = (const float4*)((const float*)srcp + (size_t)grow * FEAT + tc * 8);
                    float4 f0 = xp[0], f1 = xp[1];
                    o.x = packbf2(f0.x, f0.y); o.y = packbf2(f0.z, f0.w);
                    o.z = packbf2(f1.x, f1.y); o.w = packbf2(f1.z, f1.w);
                } else {
                    o.x = 0u; o.y = 0u; o.z = 0u; o.w = 0u;
                }
            } else {
                uint4 u = ((const uint4*)((const unsigned short*)srcp + (size_t)grow * FEAT))[tc];
                float v0 = fmaxf(fmaf(bflo(u.x), sc[0], sh[0]), 0.f);
                float v1 = fmaxf(fmaf(bfhi(u.x), sc[1], sh[1]), 0.f);
                float v2 = fmaxf(fmaf(bflo(u.y), sc[2], sh[2]), 0.f);
                float v3 = fmaxf(fmaf(bfhi(u.y), sc[3], sh[3]), 0.f);
                float v4 = fmaxf(fmaf(bflo(u.z), sc[4], sh[4]), 0.f);
                float v5 = fmaxf(fmaf(bfhi(u.z), sc[5], sh[5]), 0.f);
                float v6 = fmaxf(fmaf(bflo(u.w), sc[6], sh[6]), 0.f);
                float v7 = fmaxf(fmaf(bfhi(u.w), sc[7], sh[7]), 0.f);
                o.x = packbf2(v0, v1); o.y = packbf2(v2, v3);
                o.z = packbf2(v4, v5); o.w = packbf2(v6, v7);
            }
            XsU[row * 16 + (tc ^ (row & 7))] = o;
        }
        __syncthreads();

        // ---- MFMA: wave computes 32 rows x 64 cols ----
        f32x4 acc[2][4];
#pragma unroll
        for (int m = 0; m < 2; ++m)
#pragma unroll
            for (int n = 0; n < 4; ++n)
#pragma unroll
                for (int r2 = 0; r2 < 4; ++r2) acc[m][n][r2] = 0.f;

#pragma unroll
        for (int kt = 0; kt < 4; ++kt) {
            int rowA = wm * 32 + lr;
            bf16x8 A0 = *(const bf16x8*)&XsU[rowA * 16 + ((kt * 4 + q) ^ (rowA & 7))];
            int rowB = rowA + 16;
            bf16x8 A1 = *(const bf16x8*)&XsU[rowB * 16 + ((kt * 4 + q) ^ (rowB & 7))];
#pragma unroll
            for (int n = 0; n < 4; ++n) {
                acc[0][n] = __builtin_amdgcn_mfma_f32_16x16x32_bf16(A0, Bf[kt][n], acc[0][n], 0, 0, 0);
                acc[1][n] = __builtin_amdgcn_mfma_f32_16x16x32_bf16(A1, Bf[kt][n], acc[1][n], 0, 0, 0);
            }
        }
        __syncthreads();

        // ---- epilogue: *dinv, bf16, transpose via LDS, vector store ----
#pragma unroll
        for (int m = 0; m < 2; ++m) {
            float dv[4];
#pragma unroll
            for (int r = 0; r < 4; ++r) dv[r] = dinv[row0 + wm * 32 + m * 16 + q * 4 + r];
#pragma unroll
            for (int n = 0; n < 4; ++n) {
                int col = wn * 64 + n * 16 + lr;
#pragma unroll
                for (int r = 0; r < 4; ++r) {
                    int row = wm * 32 + m * 16 + q * 4 + r;
                    Xs[row * 128 + (((col >> 3) ^ (row & 7)) << 3) + (col & 7)] = f2bf(acc[m][n][r] * dv[r]);
                }
            }
        }
        __syncthreads();
#pragma unroll
        for (int k2 = 0; k2 < 4; ++k2) {
            int row = (t >> 4) + k2 * 16;
            ((uint4*)&Hb[(size_t)(row0 + row) * FEAT])[tc] = XsU[row * 16 + (tc ^ (row & 7))];
        }
    }
}

// ---------------- MFMA GEMM 128x40 (padded to 48), fused BN+ReLU on load ----------------

__global__ __launch_bounds__(256, 4) void gemm40_k(const unsigned short* __restrict__ srcp,
                                                   const unsigned short* __restrict__ Wt,
                                                   const float* __restrict__ ss,
                                                   const float* __restrict__ dinv,
                                                   unsigned short* __restrict__ H3,
                                                   int ntiles) {
    __shared__ uint4 XsU[64 * 16];
    unsigned short* Xs = (unsigned short*)XsU;
    const int t = threadIdx.x, tc = t & 15;
    const int l = t & 63, w = t >> 6, lr = l & 15, q = l >> 4;

    float sc[8], sh[8];
#pragma unroll
    for (int j = 0; j < 8; ++j) { sc[j] = ss[tc * 8 + j]; sh[j] = ss[128 + tc * 8 + j]; }

    bf16x8 Bf[4][3];
#pragma unroll
    for (int kt = 0; kt < 4; ++kt)
#pragma unroll
        for (int n = 0; n < 3; ++n)
            Bf[kt][n] = *(const bf16x8*)&((const uint4*)Wt)[(kt * 4 + q) * 48 + n * 16 + lr];

    for (int tile = blockIdx.x; tile < ntiles; tile += gridDim.x) {
        const int row0 = tile * 64;
        __syncthreads();
#pragma unroll
        for (int k2 = 0; k2 < 4; ++k2) {
            int row = (t >> 4) + k2 * 16;
            int grow = row0 + row;
            uint4 u = ((const uint4*)(srcp + (size_t)grow * FEAT))[tc];
            float v0 = fmaxf(fmaf(bflo(u.x), sc[0], sh[0]), 0.f);
            float v1 = fmaxf(fmaf(bfhi(u.x), sc[1], sh[1]), 0.f);
            float v2 = fmaxf(fmaf(bflo(u.y), sc[2], sh[2]), 0.f);
            float v3 = fmaxf(fmaf(bfhi(u.y), sc[3], sh[3]), 0.f);
            float v4 = fmaxf(fmaf(bflo(u.z), sc[4], sh[4]), 0.f);
            float v5 = fmaxf(fmaf(bfhi(u.z), sc[5], sh[5]), 0.f);
            float v6 = fmaxf(fmaf(bflo(u.w), sc[6], sh[6]), 0.f);
            float v7 = fmaxf(fmaf(bfhi(u.w), sc[7], sh[7]), 0.f);
            uint4 o;
            o.x = packbf2(v0, v1); o.y = packbf2(v2, v3);
            o.z = packbf2(v4, v5); o.w = packbf2(v6, v7);
            XsU[row * 16 + (tc ^ (row & 7))] = o;
        }
        __syncthreads();

        f32x4 acc[3];
#pragma unroll
        for (int n = 0; n < 3; ++n)
#pragma unroll
            for (int r2 = 0; r2 < 4; ++r2) acc[n][r2] = 0.f;

#pragma unroll
        for (int kt = 0; kt < 4; ++kt) {
            int row = w * 16 + lr;
            bf16x8 A = *(const bf16x8*)&XsU[row * 16 + ((kt * 4 + q) ^ (row & 7))];
#pragma unroll
            for (int n = 0; n < 3; ++n)
                acc[n] = __builtin_amdgcn_mfma_f32_16x16x32_bf16(A, Bf[kt][n], acc[n], 0, 0, 0);
        }
        __syncthreads();

        float dv[4];
#pragma unroll
        for (int r = 0; r < 4; ++r) dv[r] = dinv[row0 + w * 16 + q * 4 + r];
#pragma unroll
        for (int n = 0; n < 3; ++n) {
            int col = n * 16 + lr;
#pragma unroll
            for (int r = 0; r < 4; ++r) {
                int row = w * 16 + q * 4 + r;
                Xs[row * 128 + (((col >> 3) ^ (row & 7)) << 3) + (col & 7)] = f2bf(acc[n][r] * dv[r]);
            }
        }
        __syncthreads();
        // store 6 chunks/row = 48 cols
        for (int i = t; i < 384; i += 256) {
            int row = i / 6, cc = i - row * 6;
            ((uint4*)&H3[(size_t)(row0 + row) * 64])[cc] = XsU[row * 16 + (cc ^ (row & 7))];
        }
    }
}

// ---------------- aggregation (wave per node, 8 gathers in flight) + fused BN stats ----------------

__global__ __launch_bounds__(256) void agg128_k(const unsigned* __restrict__ Hb, const int* __restrict__ offs,
                                                const int* __restrict__ csr, const float* __restrict__ dinv,
                                                const float* __restrict__ bias, unsigned* __restrict__ Zb,
                                                float* __restrict__ sums, int n) {
    const int l = threadIdx.x & 63, w = threadIdx.x >> 6;
    float bx = bias[2 * l], by = bias[2 * l + 1];
    float sx = 0.f, sy = 0.f, qx = 0.f, qy = 0.f;
    for (int node = blockIdx.x * 4 + w; node < n; node += gridDim.x * 4) {
        int beg = offs[node], end = offs[node + 1];
        unsigned u = Hb[(size_t)node * 64 + l];
        float ax = bflo(u), ay = bfhi(u);
        float ax2 = 0.f, ay2 = 0.f;
        for (int e = beg; e < end; e += 8) {
            int rem = end - e;            // >= 1
            int s0 = csr[e];
            int s1 = (rem > 1) ? csr[e + 1] : s0;
            int s2 = (rem > 2) ? csr[e + 2] : s0;
            int s3 = (rem > 3) ? csr[e + 3] : s0;
            int s4 = (rem > 4) ? csr[e + 4] : s0;
            int s5 = (rem > 5) ? csr[e + 5] : s0;
            int s6 = (rem > 6) ? csr[e + 6] : s0;
            int s7 = (rem > 7) ? csr[e + 7] : s0;
            unsigned v0 = Hb[(size_t)s0 * 64 + l];
            unsigned v1 = Hb[(size_t)s1 * 64 + l];
            unsigned v2 = Hb[(size_t)s2 * 64 + l];
            unsigned v3 = Hb[(size_t)s3 * 64 + l];
            unsigned v4 = Hb[(size_t)s4 * 64 + l];
            unsigned v5 = Hb[(size_t)s5 * 64 + l];
            unsigned v6 = Hb[(size_t)s6 * 64 + l];
            unsigned v7 = Hb[(size_t)s7 * 64 + l];
            ax  += bflo(v0) + ((rem > 1) ? bflo(v1) : 0.f);
            ay  += bfhi(v0) + ((rem > 1) ? bfhi(v1) : 0.f);
            ax2 += ((rem > 2) ? bflo(v2) : 0.f) + ((rem > 3) ? bflo(v3) : 0.f);
            ay2 += ((rem > 2) ? bfhi(v2) : 0.f) + ((rem > 3) ? bfhi(v3) : 0.f);
            ax  += ((rem > 4) ? bflo(v4) : 0.f) + ((rem > 5) ? bflo(v5) : 0.f);
            ay  += ((rem > 4) ? bfhi(v4) : 0.f) + ((rem > 5) ? bfhi(v5) : 0.f);
            ax2 += ((rem > 6) ? bflo(v6) : 0.f) + ((rem > 7) ? bflo(v7) : 0.f);
            ay2 += ((rem > 6) ? bfhi(v6) : 0.f) + ((rem > 7) ? bfhi(v7) : 0.f);
        }
        ax += ax2;
        ay += ay2;
        float dv = dinv[node];
        float zx = fmaf(ax, dv, bx), zy = fmaf(ay, dv, by);
        sx += zx; sy += zy; qx += zx * zx; qy += zy * zy;
        Zb[(size_t)node * 64 + l] = packbf2(zx, zy);
    }
    __shared__ float red[4][64][4];
    red[w][l][0] = sx; red[w][l][1] = sy; red[w][l][2] = qx; red[w][l][3] = qy;
    __syncthreads();
    if (threadIdx.x < 64) {
        int tt = threadIdx.x;
        float SX = 0.f, SY = 0.f, QX = 0.f, QY = 0.f;
#pragma unroll
        for (int ww = 0; ww < 4; ++ww) {
            SX += red[ww][tt][0]; SY += red[ww][tt][1];
            QX += red[ww][tt][2]; QY += red[ww][tt][3];
        }
        atomicAdd(&sums[2 * tt], SX);
        atomicAdd(&sums[2 * tt + 1], SY);
        atomicAdd(&sums[128 + 2 * tt], QX);
        atomicAdd(&sums[128 + 2 * tt + 1], QY);
    }
}

__global__ void bnfinal_k(const float* __restrict__ sums, const float* __restrict__ g,
                          const float* __restrict__ be, float* __restrict__ ss, int n) {
    int c = threadIdx.x;   // 128 threads
    float inv_n = 1.0f / (float)n;
    float mu = sums[c] * inv_n;
    float var = sums[128 + c] * inv_n - mu * mu;
    float rstd = rsqrtf(var + BN_EPS);
    float scv = g[c] * rstd;
    ss[c] = scv;
    ss[128 + c] = be[c] - mu * scv;
}

__global__ __launch_bounds__(256) void agg40_k(const unsigned short* __restrict__ H3, const int* __restrict__ offs,
                                               const int* __restrict__ csr, const float* __restrict__ dinv,
                                               const float* __restrict__ bias, float* __restrict__ out, int n) {
    const int l = threadIdx.x & 63, w = threadIdx.x >> 6;
    const bool act = l < FOUT;
    float bl = act ? bias[l] : 0.f;
    for (int node = blockIdx.x * 4 + w; node < n; node += gridDim.x * 4) {
        int beg = offs[node], end = offs[node + 1];
        float acc = act ? bflo((unsigned)H3[(size_t)node * 64 + l]) : 0.f;
        float acc2 = 0.f;
        for (int e = beg; e < end; e += 8) {
            int rem = end - e;
            int s0 = csr[e];
            int s1 = (rem > 1) ? csr[e + 1] : s0;
            int s2 = (rem > 2) ? csr[e + 2] : s0;
            int s3 = (rem > 3) ? csr[e + 3] : s0;
            int s4 = (rem > 4) ? csr[e + 4] : s0;
            int s5 = (rem > 5) ? csr[e + 5] : s0;
            int s6 = (rem > 6) ? csr[e + 6] : s0;
            int s7 = (rem > 7) ? csr[e + 7] : s0;
            float v0 = bflo((unsigned)H3[(size_t)s0 * 64 + l]);
            float v1 = bflo((unsigned)H3[(size_t)s1 * 64 + l]);
            float v2 = bflo((unsigned)H3[(size_t)s2 * 64 + l]);
            float v3 = bflo((unsigned)H3[(size_t)s3 * 64 + l]);
            float v4 = bflo((unsigned)H3[(size_t)s4 * 64 + l]);
            float v5 = bflo((unsigned)H3[(size_t)s5 * 64 + l]);
            float v6 = bflo((unsigned)H3[(size_t)s6 * 64 + l]);
            float v7 = bflo((unsigned)H3[(size_t)s7 * 64 + l]);
            acc  += v0 + ((rem > 1) ? v1 : 0.f);
            acc2 += ((rem > 2) ? v2 : 0.f) + ((rem > 3) ? v3 : 0.f);
            acc  += ((rem > 4) ? v4 : 0.f) + ((rem > 5) ? v5 : 0.f);
            acc2 += ((rem > 6) ? v6 : 0.f) + ((rem > 7) ? v7 : 0.f);
        }
        acc += acc2;
        float val = act ? fmaf(acc, dinv[node], bl) : -INFINITY;
        float m = val;
#pragma unroll
        for (int o = 32; o > 0; o >>= 1) m = fmaxf(m, __shfl_xor(m, o));
        float ex = act ? expf(val - m) : 0.f;
        float ssum = ex;
#pragma unroll
        for (int o = 32; o > 0; o >>= 1) ssum += __shfl_xor(ssum, o);
        if (act) out[(size_t)node * FOUT + l] = val - m - logf(ssum);
    }
}

// ---------------- launch ----------------

extern "C" void kernel_launch(void* const* d_in, const int* in_sizes, int n_in,
                              void* d_out, int out_size, void* d_ws, size_t ws_size,
                              hipStream_t stream) {
    const float* x   = (const float*)d_in[0];
    const int*   src = (const int*)d_in[1];
    const int*   dst = (const int*)d_in[2];
    const float* W1  = (const float*)d_in[3];
    const float* b1  = (const float*)d_in[4];
    const float* W2  = (const float*)d_in[5];
    const float* b2  = (const float*)d_in[6];
    const float* W3  = (const float*)d_in[7];
    const float* b3  = (const float*)d_in[8];
    const float* g1  = (const float*)d_in[9];
    const float* be1 = (const float*)d_in[10];
    const float* g2  = (const float*)d_in[11];
    const float* be2 = (const float*)d_in[12];

    const int N = in_sizes[0] / FEAT;
    const int E = in_sizes[1];
    const int Np = (N + 63) & ~63;
    const int ntiles = Np / 64;
    float* out = (float*)d_out;

    char* p = (char*)d_ws;
    auto alloc = [&](size_t bytes) {
        char* r = p;
        p += (bytes + 255) & ~(size_t)255;
        return r;
    };
    float* dinv   = (float*)alloc((size_t)Np * 4);
    int*   cnt    = (int*)alloc((size_t)N * 4);
    int*   offs   = (int*)alloc((size_t)(N + 1) * 4);
    int*   cursor = (int*)alloc((size_t)N * 4);
    int*   csr    = (int*)alloc((size_t)E * 4);
    int*   bsum   = (int*)alloc(1024);
    int*   boff   = (int*)alloc(1024);
    float* sums   = (float*)alloc(1024);
    float* ss     = (float*)alloc(1024);
    unsigned short* Wt1 = (unsigned short*)alloc(4 * 4 * 128 * 8 * 2);
    unsigned short* Wt2 = (unsigned short*)alloc(4 * 4 * 128 * 8 * 2);
    unsigned short* Wt3 = (unsigned short*)alloc(4 * 4 * 48 * 8 * 2);
    unsigned short* Hb  = (unsigned short*)alloc((size_t)Np * FEAT * 2);
    unsigned short* Zb  = (unsigned short*)alloc((size_t)Np * FEAT * 2);
    unsigned short* H3  = (unsigned short*)alloc((size_t)Np * 64 * 2);

    const int nb = (N + 1023) / 1024;
    const int eb = (E + 255) / 256;

    // CSR build + dinv
    hipMemsetAsync(cnt, 0, (size_t)N * 4, stream);
    count_k<<<eb, 256, 0, stream>>>(dst, cnt, E);
    scan1_k<<<nb, 256, 0, stream>>>(cnt, bsum, N);
    scan2_k<<<1, 256, 0, stream>>>(bsum, boff, nb, offs, N, E);
    scan3_k<<<nb, 256, 0, stream>>>(cnt, boff, offs, N);
    cursor_dinv_k<<<(N + 255) / 256, 256, 0, stream>>>(offs, cnt, cursor, dinv, N);
    fill_k<<<eb, 256, 0, stream>>>(src, dst, cursor, csr, E);
    castW_k<<<48, 256, 0, stream>>>(W1, W2, W3, Wt1, Wt2, Wt3);

    // Layer 1
    gemm128_k<0><<<768, 256, 0, stream>>>(x, Wt1, nullptr, dinv, Hb, ntiles, N);
    hipMemsetAsync(sums, 0, 1024, stream);
    agg128_k<<<2048, 256, 0, stream>>>((const unsigned*)Hb, offs, csr, dinv, b1, (unsigned*)Zb, sums, N);
    bnfinal_k<<<1, 128, 0, stream>>>(sums, g1, be1, ss, N);

    // Layer 2 (BN1+ReLU fused into staging)
    gemm128_k<1><<<768, 256, 0, stream>>>(Zb, Wt2, ss, dinv, Hb, ntiles, N);
    hipMemsetAsync(sums, 0, 1024, stream);
    agg128_k<<<2048, 256, 0, stream>>>((const unsigned*)Hb, offs, csr, dinv, b2, (unsigned*)Zb, sums, N);
    bnfinal_k<<<1, 128, 0, stream>>>(sums, g2, be2, ss, N);

    // Layer 3 (BN2+ReLU fused into staging) + log_softmax
    gemm40_k<<<1024, 256, 0, stream>>>(Zb, Wt3, ss, dinv, H3, ntiles);
    agg40_k<<<2048, 256, 0, stream>>>(H3, offs, csr, dinv, b3, out, N);
}

// Round 5
// 302.389 us; speedup vs baseline: 2.3131x; 1.4256x over previous
//
#include <hip/hip_runtime.h>
#include <cstdint>
#include <cstddef>

#define FEAT 128
#define FOUT 40
constexpr float BN_EPS = 1e-5f;

typedef __attribute__((ext_vector_type(8))) short bf16x8;
typedef __attribute__((ext_vector_type(4))) float f32x4;

__device__ __forceinline__ unsigned short f2bf(float f) {
    unsigned u = __float_as_uint(f);
    u += 0x7FFFu + ((u >> 16) & 1u);
    return (unsigned short)(u >> 16);
}
__device__ __forceinline__ float bflo(unsigned u) { return __uint_as_float(u << 16); }
__device__ __forceinline__ float bfhi(unsigned u) { return __uint_as_float(u & 0xFFFF0000u); }
__device__ __forceinline__ unsigned packbf2(float a, float b) {
    return (unsigned)f2bf(a) | ((unsigned)f2bf(b) << 16);
}

// ---------------- CSR build ----------------

__global__ __launch_bounds__(256) void count_k(const int* __restrict__ dst, int* __restrict__ cnt, int E) {
    int e = blockIdx.x * 256 + threadIdx.x;
    if (e < E) atomicAdd(&cnt[dst[e]], 1);
}

__global__ __launch_bounds__(256) void scan1_k(const int* __restrict__ cnt, int* __restrict__ bsum, int n) {
    __shared__ int sh[256];
    int base = blockIdx.x * 1024, t = threadIdx.x;
    int s = 0;
#pragma unroll
    for (int j = 0; j < 4; ++j) {
        int idx = base + t * 4 + j;
        if (idx < n) s += cnt[idx];
    }
    sh[t] = s;
    __syncthreads();
    for (int o = 128; o > 0; o >>= 1) {
        if (t < o) sh[t] += sh[t + o];
        __syncthreads();
    }
    if (t == 0) bsum[blockIdx.x] = sh[0];
}

// parallel block-sum scan (nb <= 256 for N <= 262144; serial fallback otherwise)
__global__ void scan2_k(const int* __restrict__ bsum, int* __restrict__ boff, int nb,
                        int* __restrict__ offs, int n, int E) {
    __shared__ int sh[256];
    int t = threadIdx.x;
    if (nb <= 256) {
        int v = (t < nb) ? bsum[t] : 0;
        sh[t] = v;
        __syncthreads();
        for (int o = 1; o < 256; o <<= 1) {
            int x = (t >= o) ? sh[t - o] : 0;
            __syncthreads();
            sh[t] += x;
            __syncthreads();
        }
        if (t < nb) boff[t] = sh[t] - v;
        if (t == 0) offs[n] = E;
    } else if (t == 0) {
        int run = 0;
        for (int i = 0; i < nb; ++i) { boff[i] = run; run += bsum[i]; }
        offs[n] = E;
    }
}

__global__ __launch_bounds__(256) void scan3_k(const int* __restrict__ cnt, const int* __restrict__ boff,
                                               int* __restrict__ offs, int n) {
    __shared__ int sh[256];
    int base = blockIdx.x * 1024, t = threadIdx.x;
    int c[4];
    int s = 0;
#pragma unroll
    for (int j = 0; j < 4; ++j) {
        int idx = base + t * 4 + j;
        c[j] = (idx < n) ? cnt[idx] : 0;
        s += c[j];
    }
    sh[t] = s;
    __syncthreads();
    for (int o = 1; o < 256; o <<= 1) {
        int v = (t >= o) ? sh[t - o] : 0;
        __syncthreads();
        sh[t] += v;
        __syncthreads();
    }
    int g = boff[blockIdx.x] + sh[t] - s;
#pragma unroll
    for (int j = 0; j < 4; ++j) {
        int idx = base + t * 4 + j;
        if (idx < n) offs[idx] = g;
        g += c[j];
    }
}

__global__ __launch_bounds__(256) void cursor_dinv_k(const int* __restrict__ offs, const int* __restrict__ cnt,
                                                     int* __restrict__ cursor, float* __restrict__ dinv, int n) {
    int i = blockIdx.x * 256 + threadIdx.x;
    if (i < n) {
        cursor[i] = offs[i];
        dinv[i] = rsqrtf((float)(cnt[i] + 1));
    }
}

__global__ __launch_bounds__(256) void fill_k(const int* __restrict__ src, const int* __restrict__ dst,
                                              int* __restrict__ cursor, int* __restrict__ csr, int E) {
    int e = blockIdx.x * 256 + threadIdx.x;
    if (e < E) {
        int d = dst[e];
        int p = atomicAdd(&cursor[d], 1);
        csr[p] = src[e];
    }
}

// ---------------- weight pack to bf16 MFMA B-fragment order ----------------
// Wt layout: [kt 0..3][q 0..3][col][j 0..7], element = W[kt*32+q*8+j][col]

__global__ __launch_bounds__(256) void castW_k(const float* __restrict__ W1, const float* __restrict__ W2,
                                               const float* __restrict__ W3,
                                               unsigned short* __restrict__ Wt1, unsigned short* __restrict__ Wt2,
                                               unsigned short* __restrict__ Wt3) {
    int tid = blockIdx.x * 256 + threadIdx.x;
    int stride = gridDim.x * 256;
    for (int i = tid; i < 4 * 4 * 128 * 8; i += stride) {
        int j = i & 7, c = (i >> 3) & 127, q = (i >> 10) & 3, kt = i >> 12;
        int k = kt * 32 + q * 8 + j;
        Wt1[i] = f2bf(W1[k * 128 + c]);
        Wt2[i] = f2bf(W2[k * 128 + c]);
    }
    for (int i = tid; i < 4 * 4 * 48 * 8; i += stride) {
        int j = i & 7, rest = i >> 3;
        int c = rest % 48, kq = rest / 48;
        int q = kq & 3, kt = kq >> 2;
        int k = kt * 32 + q * 8 + j;
        Wt3[i] = (c < FOUT) ? f2bf(W3[k * FOUT + c]) : (unsigned short)0;
    }
}

// ---------------- MFMA GEMM 128x128, epilogue * dinv, bf16 out ----------------
// SRC 0: read fp32 (layer 1).  SRC 1: read bf16 + fused BN(scale/shift)+ReLU.

template <int SRC>
__global__ __launch_bounds__(256, 3) void gemm128_k(const void* __restrict__ srcp,
                                                    const unsigned short* __restrict__ Wt,
                                                    const float* __restrict__ ss,
                                                    const float* __restrict__ dinv,
                                                    unsigned short* __restrict__ Hb,
                                                    int ntiles, int nreal) {
    __shared__ uint4 XsU[64 * 16];              // 16 KiB, chunk-swizzled
    unsigned short* Xs = (unsigned short*)XsU;

    const int t = threadIdx.x;
    const int tc = t & 15;                      // chunk (8 cols) this thread stages
    const int l = t & 63, w = t >> 6;
    const int wm = w >> 1, wn = w & 1;
    const int lr = l & 15, q = l >> 4;

    float sc[8], sh[8];
    if (SRC == 1) {
#pragma unroll
        for (int j = 0; j < 8; ++j) { sc[j] = ss[tc * 8 + j]; sh[j] = ss[128 + tc * 8 + j]; }
    }

    // B fragments held in registers for the whole kernel (W is tile-invariant)
    bf16x8 Bf[4][4];
#pragma unroll
    for (int kt = 0; kt < 4; ++kt)
#pragma unroll
        for (int n = 0; n < 4; ++n) {
            int col = wn * 64 + n * 16 + lr;
            Bf[kt][n] = *(const bf16x8*)&((const uint4*)Wt)[(kt * 4 + q) * 128 + col];
        }

    for (int tile = blockIdx.x; tile < ntiles; tile += gridDim.x) {
        const int row0 = tile * 64;
        __syncthreads();
        // ---- stage 64x128 X tile (reg -> LDS, swizzled), fusing cast / BN+ReLU ----
#pragma unroll
        for (int k2 = 0; k2 < 4; ++k2) {
            int row = (t >> 4) + k2 * 16;
            int grow = row0 + row;
            uint4 o;
            if (SRC == 0) {
                if (grow < nreal) {
                    const float4* xp = (const float4*)((const float*)srcp + (size_t)grow * FEAT + tc * 8);
                    float4 f0 = xp[0], f1 = xp[1];
                    o.x = packbf2(f0.x, f0.y); o.y = packbf2(f0.z, f0.w);
                    o.z = packbf2(f1.x, f1.y); o.w = packbf2(f1.z, f1.w);
                } else {
                    o.x = 0u; o.y = 0u; o.z = 0u; o.w = 0u;
                }
            } else {
                uint4 u = ((const uint4*)((const unsigned short*)srcp + (size_t)grow * FEAT))[tc];
                float v0 = fmaxf(fmaf(bflo(u.x), sc[0], sh[0]), 0.f);
                float v1 = fmaxf(fmaf(bfhi(u.x), sc[1], sh[1]), 0.f);
                float v2 = fmaxf(fmaf(bflo(u.y), sc[2], sh[2]), 0.f);
                float v3 = fmaxf(fmaf(bfhi(u.y), sc[3], sh[3]), 0.f);
                float v4 = fmaxf(fmaf(bflo(u.z), sc[4], sh[4]), 0.f);
                float v5 = fmaxf(fmaf(bfhi(u.z), sc[5], sh[5]), 0.f);
                float v6 = fmaxf(fmaf(bflo(u.w), sc[6], sh[6]), 0.f);
                float v7 = fmaxf(fmaf(bfhi(u.w), sc[7], sh[7]), 0.f);
                o.x = packbf2(v0, v1); o.y = packbf2(v2, v3);
                o.z = packbf2(v4, v5); o.w = packbf2(v6, v7);
            }
            XsU[row * 16 + (tc ^ (row & 7))] = o;
        }
        __syncthreads();

        // ---- MFMA: wave computes 32 rows x 64 cols ----
        f32x4 acc[2][4];
#pragma unroll
        for (int m = 0; m < 2; ++m)
#pragma unroll
            for (int n = 0; n < 4; ++n)
#pragma unroll
                for (int r2 = 0; r2 < 4; ++r2) acc[m][n][r2] = 0.f;

#pragma unroll
        for (int kt = 0; kt < 4; ++kt) {
            int rowA = wm * 32 + lr;
            bf16x8 A0 = *(const bf16x8*)&XsU[rowA * 16 + ((kt * 4 + q) ^ (rowA & 7))];
            int rowB = rowA + 16;
            bf16x8 A1 = *(const bf16x8*)&XsU[rowB * 16 + ((kt * 4 + q) ^ (rowB & 7))];
#pragma unroll
            for (int n = 0; n < 4; ++n) {
                acc[0][n] = __builtin_amdgcn_mfma_f32_16x16x32_bf16(A0, Bf[kt][n], acc[0][n], 0, 0, 0);
                acc[1][n] = __builtin_amdgcn_mfma_f32_16x16x32_bf16(A1, Bf[kt][n], acc[1][n], 0, 0, 0);
            }
        }
        __syncthreads();

        // ---- epilogue: *dinv, bf16, transpose via LDS, vector store ----
#pragma unroll
        for (int m = 0; m < 2; ++m) {
            float dv[4];
#pragma unroll
            for (int r = 0; r < 4; ++r) dv[r] = dinv[row0 + wm * 32 + m * 16 + q * 4 + r];
#pragma unroll
            for (int n = 0; n < 4; ++n) {
                int col = wn * 64 + n * 16 + lr;
#pragma unroll
                for (int r = 0; r < 4; ++r) {
                    int row = wm * 32 + m * 16 + q * 4 + r;
                    Xs[row * 128 + (((col >> 3) ^ (row & 7)) << 3) + (col & 7)] = f2bf(acc[m][n][r] * dv[r]);
                }
            }
        }
        __syncthreads();
#pragma unroll
        for (int k2 = 0; k2 < 4; ++k2) {
            int row = (t >> 4) + k2 * 16;
            ((uint4*)&Hb[(size_t)(row0 + row) * FEAT])[tc] = XsU[row * 16 + (tc ^ (row & 7))];
        }
    }
}

// ---------------- MFMA GEMM 128x40 (padded to 48), fused BN+ReLU on load ----------------

__global__ __launch_bounds__(256, 4) void gemm40_k(const unsigned short* __restrict__ srcp,
                                                   const unsigned short* __restrict__ Wt,
                                                   const float* __restrict__ ss,
                                                   const float* __restrict__ dinv,
                                                   unsigned short* __restrict__ H3,
                                                   int ntiles) {
    __shared__ uint4 XsU[64 * 16];
    unsigned short* Xs = (unsigned short*)XsU;
    const int t = threadIdx.x, tc = t & 15;
    const int l = t & 63, w = t >> 6, lr = l & 15, q = l >> 4;

    float sc[8], sh[8];
#pragma unroll
    for (int j = 0; j < 8; ++j) { sc[j] = ss[tc * 8 + j]; sh[j] = ss[128 + tc * 8 + j]; }

    bf16x8 Bf[4][3];
#pragma unroll
    for (int kt = 0; kt < 4; ++kt)
#pragma unroll
        for (int n = 0; n < 3; ++n)
            Bf[kt][n] = *(const bf16x8*)&((const uint4*)Wt)[(kt * 4 + q) * 48 + n * 16 + lr];

    for (int tile = blockIdx.x; tile < ntiles; tile += gridDim.x) {
        const int row0 = tile * 64;
        __syncthreads();
#pragma unroll
        for (int k2 = 0; k2 < 4; ++k2) {
            int row = (t >> 4) + k2 * 16;
            int grow = row0 + row;
            uint4 u = ((const uint4*)(srcp + (size_t)grow * FEAT))[tc];
            float v0 = fmaxf(fmaf(bflo(u.x), sc[0], sh[0]), 0.f);
            float v1 = fmaxf(fmaf(bfhi(u.x), sc[1], sh[1]), 0.f);
            float v2 = fmaxf(fmaf(bflo(u.y), sc[2], sh[2]), 0.f);
            float v3 = fmaxf(fmaf(bfhi(u.y), sc[3], sh[3]), 0.f);
            float v4 = fmaxf(fmaf(bflo(u.z), sc[4], sh[4]), 0.f);
            float v5 = fmaxf(fmaf(bfhi(u.z), sc[5], sh[5]), 0.f);
            float v6 = fmaxf(fmaf(bflo(u.w), sc[6], sh[6]), 0.f);
            float v7 = fmaxf(fmaf(bfhi(u.w), sc[7], sh[7]), 0.f);
            uint4 o;
            o.x = packbf2(v0, v1); o.y = packbf2(v2, v3);
            o.z = packbf2(v4, v5); o.w = packbf2(v6, v7);
            XsU[row * 16 + (tc ^ (row & 7))] = o;
        }
        __syncthreads();

        f32x4 acc[3];
#pragma unroll
        for (int n = 0; n < 3; ++n)
#pragma unroll
            for (int r2 = 0; r2 < 4; ++r2) acc[n][r2] = 0.f;

#pragma unroll
        for (int kt = 0; kt < 4; ++kt) {
            int row = w * 16 + lr;
            bf16x8 A = *(const bf16x8*)&XsU[row * 16 + ((kt * 4 + q) ^ (row & 7))];
#pragma unroll
            for (int n = 0; n < 3; ++n)
                acc[n] = __builtin_amdgcn_mfma_f32_16x16x32_bf16(A, Bf[kt][n], acc[n], 0, 0, 0);
        }
        __syncthreads();

        float dv[4];
#pragma unroll
        for (int r = 0; r < 4; ++r) dv[r] = dinv[row0 + w * 16 + q * 4 + r];
#pragma unroll
        for (int n = 0; n < 3; ++n) {
            int col = n * 16 + lr;
#pragma unroll
            for (int r = 0; r < 4; ++r) {
                int row = w * 16 + q * 4 + r;
                Xs[row * 128 + (((col >> 3) ^ (row & 7)) << 3) + (col & 7)] = f2bf(acc[n][r] * dv[r]);
            }
        }
        __syncthreads();
        // store 6 chunks/row = 48 cols
        for (int i = t; i < 384; i += 256) {
            int row = i / 6, cc = i - row * 6;
            ((uint4*)&H3[(size_t)(row0 + row) * 64])[cc] = XsU[row * 16 + (cc ^ (row & 7))];
        }
    }
}

// ---------------- aggregation: 16-lane group per node (4 nodes/wave), uint4 gathers ----------------

__global__ __launch_bounds__(256) void agg128_k(const uint4* __restrict__ Hb4, const int* __restrict__ offs,
                                                const int* __restrict__ csr, const float* __restrict__ dinv,
                                                const float* __restrict__ bias, uint4* __restrict__ Zb4,
                                                float* __restrict__ sums, int n) {
    const int t = threadIdx.x;
    const int g16 = t >> 4;        // group 0..15 in block
    const int l16 = t & 15;        // lane in group; features l16*8 .. +7
    float bs[8];
#pragma unroll
    for (int j = 0; j < 8; ++j) bs[j] = bias[l16 * 8 + j];
    float s[8] = {0.f,0.f,0.f,0.f,0.f,0.f,0.f,0.f};
    float qq[8] = {0.f,0.f,0.f,0.f,0.f,0.f,0.f,0.f};

    for (int node = blockIdx.x * 16 + g16; node < n; node += gridDim.x * 16) {
        int beg = offs[node], end = offs[node + 1];
        uint4 u = Hb4[(size_t)node * 16 + l16];
        float a[8];
        a[0] = bflo(u.x); a[1] = bfhi(u.x); a[2] = bflo(u.y); a[3] = bfhi(u.y);
        a[4] = bflo(u.z); a[5] = bfhi(u.z); a[6] = bflo(u.w); a[7] = bfhi(u.w);
        for (int e = beg; e < end; e += 8) {
            int rem = end - e;            // >= 1
            int s0 = csr[e];
            int s1 = (rem > 1) ? csr[e + 1] : s0;
            int s2 = (rem > 2) ? csr[e + 2] : s0;
            int s3 = (rem > 3) ? csr[e + 3] : s0;
            int s4 = (rem > 4) ? csr[e + 4] : s0;
            int s5 = (rem > 5) ? csr[e + 5] : s0;
            int s6 = (rem > 6) ? csr[e + 6] : s0;
            int s7 = (rem > 7) ? csr[e + 7] : s0;
            uint4 v0 = Hb4[(size_t)s0 * 16 + l16];
            uint4 v1 = Hb4[(size_t)s1 * 16 + l16];
            uint4 v2 = Hb4[(size_t)s2 * 16 + l16];
            uint4 v3 = Hb4[(size_t)s3 * 16 + l16];
            uint4 v4 = Hb4[(size_t)s4 * 16 + l16];
            uint4 v5 = Hb4[(size_t)s5 * 16 + l16];
            uint4 v6 = Hb4[(size_t)s6 * 16 + l16];
            uint4 v7 = Hb4[(size_t)s7 * 16 + l16];
#define ACC8(v) { a[0]+=bflo(v.x); a[1]+=bfhi(v.x); a[2]+=bflo(v.y); a[3]+=bfhi(v.y); \
                  a[4]+=bflo(v.z); a[5]+=bfhi(v.z); a[6]+=bflo(v.w); a[7]+=bfhi(v.w); }
            ACC8(v0);
            if (rem > 1) ACC8(v1);
            if (rem > 2) ACC8(v2);
            if (rem > 3) ACC8(v3);
            if (rem > 4) ACC8(v4);
            if (rem > 5) ACC8(v5);
            if (rem > 6) ACC8(v6);
            if (rem > 7) ACC8(v7);
#undef ACC8
        }
        float dv = dinv[node];
        float z[8];
#pragma unroll
        for (int j = 0; j < 8; ++j) {
            z[j] = fmaf(a[j], dv, bs[j]);
            s[j] += z[j];
            qq[j] += z[j] * z[j];
        }
        uint4 o;
        o.x = packbf2(z[0], z[1]); o.y = packbf2(z[2], z[3]);
        o.z = packbf2(z[4], z[5]); o.w = packbf2(z[6], z[7]);
        Zb4[(size_t)node * 16 + l16] = o;
    }

    // BN stats: per-group partials -> LDS -> one atomic per feature per block
    __shared__ float red[2][16][128];
#pragma unroll
    for (int j = 0; j < 8; ++j) {
        red[0][g16][l16 * 8 + j] = s[j];
        red[1][g16][l16 * 8 + j] = qq[j];
    }
    __syncthreads();
    int f = t & 127, which = t >> 7;
    float acc = 0.f;
#pragma unroll
    for (int G = 0; G < 16; ++G) acc += red[which][G][f];
    atomicAdd(&sums[which * 128 + f], acc);
}

__global__ void bnfinal_k(const float* __restrict__ sums, const float* __restrict__ g,
                          const float* __restrict__ be, float* __restrict__ ss, int n) {
    int c = threadIdx.x;   // 128 threads
    float inv_n = 1.0f / (float)n;
    float mu = sums[c] * inv_n;
    float var = sums[128 + c] * inv_n - mu * mu;
    float rstd = rsqrtf(var + BN_EPS);
    float scv = g[c] * rstd;
    ss[c] = scv;
    ss[128 + c] = be[c] - mu * scv;
}

// 16-lane group per node; lane covers features l16*4..+3 (H3 row = 64 bf16 = uint2 x16)

__global__ __launch_bounds__(256) void agg40_k(const uint2* __restrict__ H32, const int* __restrict__ offs,
                                               const int* __restrict__ csr, const float* __restrict__ dinv,
                                               const float* __restrict__ bias, float* __restrict__ out, int n) {
    const int t = threadIdx.x;
    const int g16 = t >> 4, l16 = t & 15;
    const int f0 = l16 * 4;
    float bl[4];
#pragma unroll
    for (int j = 0; j < 4; ++j) bl[j] = (f0 + j < FOUT) ? bias[f0 + j] : 0.f;

    for (int node = blockIdx.x * 16 + g16; node < n; node += gridDim.x * 16) {
        int beg = offs[node], end = offs[node + 1];
        uint2 u = H32[(size_t)node * 16 + l16];
        float a[4];
        a[0] = bflo(u.x); a[1] = bfhi(u.x); a[2] = bflo(u.y); a[3] = bfhi(u.y);
        for (int e = beg; e < end; e += 8) {
            int rem = end - e;
            int s0 = csr[e];
            int s1 = (rem > 1) ? csr[e + 1] : s0;
            int s2 = (rem > 2) ? csr[e + 2] : s0;
            int s3 = (rem > 3) ? csr[e + 3] : s0;
            int s4 = (rem > 4) ? csr[e + 4] : s0;
            int s5 = (rem > 5) ? csr[e + 5] : s0;
            int s6 = (rem > 6) ? csr[e + 6] : s0;
            int s7 = (rem > 7) ? csr[e + 7] : s0;
            uint2 v0 = H32[(size_t)s0 * 16 + l16];
            uint2 v1 = H32[(size_t)s1 * 16 + l16];
            uint2 v2 = H32[(size_t)s2 * 16 + l16];
            uint2 v3 = H32[(size_t)s3 * 16 + l16];
            uint2 v4 = H32[(size_t)s4 * 16 + l16];
            uint2 v5 = H32[(size_t)s5 * 16 + l16];
            uint2 v6 = H32[(size_t)s6 * 16 + l16];
            uint2 v7 = H32[(size_t)s7 * 16 + l16];
#define ACC4(v) { a[0]+=bflo(v.x); a[1]+=bfhi(v.x); a[2]+=bflo(v.y); a[3]+=bfhi(v.y); }
            ACC4(v0);
            if (rem > 1) ACC4(v1);
            if (rem > 2) ACC4(v2);
            if (rem > 3) ACC4(v3);
            if (rem > 4) ACC4(v4);
            if (rem > 5) ACC4(v5);
            if (rem > 6) ACC4(v6);
            if (rem > 7) ACC4(v7);
#undef ACC4
        }
        float dv = dinv[node];
        float val[4];
#pragma unroll
        for (int j = 0; j < 4; ++j)
            val[j] = (f0 + j < FOUT) ? fmaf(a[j], dv, bl[j]) : -INFINITY;
        float m = fmaxf(fmaxf(val[0], val[1]), fmaxf(val[2], val[3]));
#pragma unroll
        for (int o = 8; o > 0; o >>= 1) m = fmaxf(m, __shfl_xor(m, o, 16));
        float es = 0.f;
#pragma unroll
        for (int j = 0; j < 4; ++j) es += (f0 + j < FOUT) ? expf(val[j] - m) : 0.f;
#pragma unroll
        for (int o = 8; o > 0; o >>= 1) es += __shfl_xor(es, o, 16);
        float lse = m + logf(es);
#pragma unroll
        for (int j = 0; j < 4; ++j)
            if (f0 + j < FOUT) out[(size_t)node * FOUT + f0 + j] = val[j] - lse;
    }
}

// ---------------- launch ----------------

extern "C" void kernel_launch(void* const* d_in, const int* in_sizes, int n_in,
                              void* d_out, int out_size, void* d_ws, size_t ws_size,
                              hipStream_t stream) {
    const float* x   = (const float*)d_in[0];
    const int*   src = (const int*)d_in[1];
    const int*   dst = (const int*)d_in[2];
    const float* W1  = (const float*)d_in[3];
    const float* b1  = (const float*)d_in[4];
    const float* W2  = (const float*)d_in[5];
    const float* b2  = (const float*)d_in[6];
    const float* W3  = (const float*)d_in[7];
    const float* b3  = (const float*)d_in[8];
    const float* g1  = (const float*)d_in[9];
    const float* be1 = (const float*)d_in[10];
    const float* g2  = (const float*)d_in[11];
    const float* be2 = (const float*)d_in[12];

    const int N = in_sizes[0] / FEAT;
    const int E = in_sizes[1];
    const int Np = (N + 63) & ~63;
    const int ntiles = Np / 64;
    float* out = (float*)d_out;

    char* p = (char*)d_ws;
    auto alloc = [&](size_t bytes) {
        char* r = p;
        p += (bytes + 255) & ~(size_t)255;
        return r;
    };
    float* dinv   = (float*)alloc((size_t)Np * 4);
    int*   cnt    = (int*)alloc((size_t)N * 4);
    int*   offs   = (int*)alloc((size_t)(N + 1) * 4);
    int*   cursor = (int*)alloc((size_t)N * 4);
    int*   csr    = (int*)alloc((size_t)E * 4);
    int*   bsum   = (int*)alloc(1024);
    int*   boff   = (int*)alloc(1024);
    float* sums   = (float*)alloc(1024);
    float* ss     = (float*)alloc(1024);
    unsigned short* Wt1 = (unsigned short*)alloc(4 * 4 * 128 * 8 * 2);
    unsigned short* Wt2 = (unsigned short*)alloc(4 * 4 * 128 * 8 * 2);
    unsigned short* Wt3 = (unsigned short*)alloc(4 * 4 * 48 * 8 * 2);
    unsigned short* Hb  = (unsigned short*)alloc((size_t)Np * FEAT * 2);
    unsigned short* Zb  = (unsigned short*)alloc((size_t)Np * FEAT * 2);
    unsigned short* H3  = (unsigned short*)alloc((size_t)Np * 64 * 2);

    const int nb = (N + 1023) / 1024;
    const int eb = (E + 255) / 256;

    // CSR build + dinv
    hipMemsetAsync(cnt, 0, (size_t)N * 4, stream);
    count_k<<<eb, 256, 0, stream>>>(dst, cnt, E);
    scan1_k<<<nb, 256, 0, stream>>>(cnt, bsum, N);
    scan2_k<<<1, 256, 0, stream>>>(bsum, boff, nb, offs, N, E);
    scan3_k<<<nb, 256, 0, stream>>>(cnt, boff, offs, N);
    cursor_dinv_k<<<(N + 255) / 256, 256, 0, stream>>>(offs, cnt, cursor, dinv, N);
    fill_k<<<eb, 256, 0, stream>>>(src, dst, cursor, csr, E);
    castW_k<<<48, 256, 0, stream>>>(W1, W2, W3, Wt1, Wt2, Wt3);

    // Layer 1
    gemm128_k<0><<<768, 256, 0, stream>>>(x, Wt1, nullptr, dinv, Hb, ntiles, N);
    hipMemsetAsync(sums, 0, 1024, stream);
    agg128_k<<<2048, 256, 0, stream>>>((const uint4*)Hb, offs, csr, dinv, b1, (uint4*)Zb, sums, N);
    bnfinal_k<<<1, 128, 0, stream>>>(sums, g1, be1, ss, N);

    // Layer 2 (BN1+ReLU fused into staging)
    gemm128_k<1><<<768, 256, 0, stream>>>(Zb, Wt2, ss, dinv, Hb, ntiles, N);
    hipMemsetAsync(sums, 0, 1024, stream);
    agg128_k<<<2048, 256, 0, stream>>>((const uint4*)Hb, offs, csr, dinv, b2, (uint4*)Zb, sums, N);
    bnfinal_k<<<1, 128, 0, stream>>>(sums, g2, be2, ss, N);

    // Layer 3 (BN2+ReLU fused into staging) + log_softmax
    gemm40_k<<<1024, 256, 0, stream>>>(Zb, Wt3, ss, dinv, H3, ntiles);
    agg40_k<<<2048, 256, 0, stream>>>((const uint2*)H3, offs, csr, dinv, b3, out, N);
}